// Round 6
// baseline (90592.944 us; speedup 1.0000x reference)
//
#include <hip/hip_runtime.h>
#include <math.h>

#define TSTEPS 1024
#define NXD 128
#define NAD 64
#define NBLK 16
#define TPB 512
#define LSTR 67         // LDS row stride for L
#define QSTR 65         // LDS row stride for staged Qaa
#define KSTR 68         // LDS row stride for K / Qax columns
#define GAINW 129

// ---------- lane-broadcast helpers ----------
__device__ __forceinline__ float rdl(float v, int l) {
  return __int_as_float(__builtin_amdgcn_readlane(__float_as_int(v), l));
}
__device__ __forceinline__ double rdl(double v, int l) {
  unsigned long long b = (unsigned long long)__double_as_longlong(v);
  int lo = __builtin_amdgcn_readlane((int)(b & 0xffffffffULL), l);
  int hi = __builtin_amdgcn_readlane((int)(b >> 32), l);
  unsigned long long r = (((unsigned long long)(unsigned)hi) << 32) | (unsigned)lo;
  return __longlong_as_double((long long)r);
}

// ---------- relaxed agent-scope (L2-bypass, L3-coherent) accessors ----------
__device__ __forceinline__ float gldf(const float* p) {
  return __hip_atomic_load(p, __ATOMIC_RELAXED, __HIP_MEMORY_SCOPE_AGENT);
}
__device__ __forceinline__ void gstf(float* p, float v) {
  __hip_atomic_store(p, v, __ATOMIC_RELAXED, __HIP_MEMORY_SCOPE_AGENT);
}
__device__ __forceinline__ double gldd(const double* p) {
  return __hip_atomic_load(p, __ATOMIC_RELAXED, __HIP_MEMORY_SCOPE_AGENT);
}

// ---------- flat device-wide barrier, 16 arrivals ----------
__device__ __forceinline__ void gbar(unsigned* arrive, unsigned* epoch, unsigned e) {
  asm volatile("s_waitcnt vmcnt(0)" ::: "memory");   // drain this wave's sc1 stores
  __syncthreads();
  if (threadIdx.x == 0) {
    unsigned prev = __hip_atomic_fetch_add(arrive, 1u, __ATOMIC_RELAXED, __HIP_MEMORY_SCOPE_AGENT);
    if (prev == e * NBLK - 1u) {
      __hip_atomic_store(epoch, e, __ATOMIC_RELAXED, __HIP_MEMORY_SCOPE_AGENT);
    } else {
      while (__hip_atomic_load(epoch, __ATOMIC_RELAXED, __HIP_MEMORY_SCOPE_AGENT) < e) {
        __builtin_amdgcn_s_sleep(1);
      }
    }
  }
  __syncthreads();
}

// ---------- unpivoted LDL^T factor, lane = row, regs, reads LDS Qaa ----------
__device__ __forceinline__ float factor32(const float* __restrict__ QaaS, int lane,
                                          float* __restrict__ Lsh) {
  float a[64];
#pragma unroll
  for (int k = 0; k < 64; ++k) a[k] = QaaS[lane * QSTR + k];
  float mmax = 0.f;
#pragma unroll
  for (int j = 0; j < 63; ++j) {
    float d = rdl(a[j], j);
    d = (d == 0.f) ? 1e-30f : d;
    float rdv = 1.0f / d;
    float m = a[j] * rdv;
    m = (lane > j) ? m : 0.f;
    mmax = fmaxf(mmax, fabsf(m));
#pragma unroll
    for (int k = j + 1; k < 64; ++k) {
      float u = rdl(a[j], k);          // = A[k][j] == A[j][k] (symmetric trick)
      a[k] = fmaf(-m, u, a[k]);
    }
    if (lane > j) a[j] = m;
  }
#pragma unroll
  for (int k = 0; k < 64; ++k) Lsh[lane * LSTR + k] = a[k];
#pragma unroll
  for (int s = 1; s < 64; s <<= 1) mmax = fmaxf(mmax, __shfl_xor(mmax, s));
  return mmax;
}

__device__ __forceinline__ void factor64(const float* __restrict__ QaaS, int lane,
                                         double* __restrict__ Lsh) {
  double a[64];
#pragma unroll
  for (int k = 0; k < 64; ++k) a[k] = (double)QaaS[lane * QSTR + k];   // loads complete before Lsh stores (same wave)
#pragma unroll
  for (int j = 0; j < 63; ++j) {
    double d = rdl(a[j], j);
    d = (d == 0.0) ? 1e-300 : d;
    double rdv = 1.0 / d;
    double m = a[j] * rdv;
    m = (lane > j) ? m : 0.0;
#pragma unroll
    for (int k = j + 1; k < 64; ++k) {
      double u = rdl(a[j], k);
      a[k] = fma(-m, u, a[k]);
    }
    if (lane > j) a[j] = m;
  }
#pragma unroll
  for (int k = 0; k < 64; ++k) Lsh[lane * LSTR + k] = a[k];
}

// ---------- multi-RHS triangular solve: 9 ILP chains share the L reads ----------
template <typename T>
__device__ __forceinline__ void trisolveN(const T* __restrict__ Lsh, int lane,
                                          const float bv[9], float g[9]) {
  T x[9];
#pragma unroll
  for (int r = 0; r < 9; ++r) x[r] = (T)bv[r];
  for (int j = 0; j < 63; ++j) {       // forward: L y = b (unit diag)
    T lij = Lsh[lane * LSTR + j];
#pragma unroll
    for (int r = 0; r < 9; ++r) {
      T xj = rdl(x[r], j);
      if (lane > j) x[r] = x[r] - lij * xj;
    }
  }
  T d = Lsh[lane * LSTR + lane];
  if (d == (T)0) d = (T)1e-30;
#pragma unroll
  for (int r = 0; r < 9; ++r) x[r] = x[r] / d;   // D z = y
  for (int j = 63; j > 0; --j) {       // backward: L^T w = z
    T lji = Lsh[j * LSTR + lane];
#pragma unroll
    for (int r = 0; r < 9; ++r) {
      T xj = rdl(x[r], j);
      if (lane < j) x[r] = x[r] - lji * xj;
    }
  }
#pragma unroll
  for (int r = 0; r < 9; ++r) g[r] = -(float)x[r];
}

// ---------- w = Vxx @ col, Vxx staged in LDS (symmetric -> rows as columns) ----------
__device__ __forceinline__ void matvec128_lds(const float* __restrict__ VxxS, float fcl, float fch,
                                              int lane, float& w0, float& w1) {
  w0 = 0.f; w1 = 0.f;
  const float* vrow = VxxS + 2 * lane;
#pragma unroll 8
  for (int c = 0; c < 64; ++c) {
    float s = rdl(fcl, c);
    float2 v = *(const float2*)(vrow + c * NXD);
    w0 = fmaf(v.x, s, w0); w1 = fmaf(v.y, s, w1);
  }
#pragma unroll 8
  for (int c = 0; c < 64; ++c) {
    float s = rdl(fch, c);
    float2 v = *(const float2*)(vrow + (64 + c) * NXD);
    w0 = fmaf(v.x, s, w0); w1 = fmaf(v.y, s, w1);
  }
}

__global__ void init_bar_kernel(unsigned* bar) {
  __hip_atomic_store(bar + threadIdx.x, 0u, __ATOMIC_RELAXED, __HIP_MEMORY_SCOPE_AGENT);
}

__global__ __launch_bounds__(TPB, 1) void ilqr_main(
    const float* __restrict__ fx, const float* __restrict__ fa,
    const float* __restrict__ lx, const float* __restrict__ la,
    const float* __restrict__ lxx, const float* __restrict__ laa,
    const float* __restrict__ lax, float* __restrict__ out,
    float* __restrict__ wsf, unsigned* __restrict__ bar) {

  // 96.6 KiB LDS; P2/P3 buffers aliased over dead P1 regions
  __shared__ float SM[24704];
  float*  VxxS    = SM;                 // [128][128]          (P1)
  float*  faS     = SM + 16384;         // [128][64]           (P1)
  float*  VxS     = SM + 24576;         // [128]
  float*  QaaS    = SM;                 // 64*QSTR = 4160      (P2, over VxxS)
  float*  LfS     = SM + 4160;          // 64*LSTR = 4288      (P2)
  float*  QaxColS = SM + 12032;         // 64*KSTR = 4352      (P2/P3)
  float*  KcolS   = SM + 16384;         // 65*KSTR = 4420      (P2/P3, over faS)
  double* LdS     = (double*)SM;        // 64*LSTR dbl = 8576 fl (rare f64 path; loads QaaS first)
  __shared__ int flag64;

  const int b = blockIdx.x;
  const int tid = threadIdx.x;
  const int w = tid >> 6;               // 8 waves
  const int lane = tid & 63;
  const int ti = b >> 2, tj = b & 3;    // 4x4 grid of 32x32 Vxx tiles

  // workspace (floats) — cross-block data via sc1 (agent-relaxed)
  float* Vxx  = wsf;               // 128*128, kept exactly symmetric
  float* Vx   = Vxx + 16384;       // 128
  float* QxxC = Vx + 128;          // 128*128, QxxC[j][i] = Qxx[i][j]
  float* QaxT = QxxC + 16384;      // 128*64,  QaxT[x][a] = Qax[a][x]
  float* QaaC = QaxT + 8192;       // 64*64,   QaaC[j][a] = Qaa[a][j]
  float* Qx   = QaaC + 4096;       // 128
  float* Qa   = Qx + 128;          // 64

  unsigned* arrive = bar;
  unsigned* epoch  = bar + 32;
  unsigned ep = 0;

  // ---- init carry: Vxx = lxx[T-1], Vx = lx[T-1] ----
  {
    const float* src = lxx + (size_t)(TSTEPS - 1) * NXD * NXD;
    int idx = b * (2 * TPB) + tid;
    gstf(Vxx + idx, src[idx]);
    gstf(Vxx + idx + TPB, src[idx + TPB]);
    if (b == 0 && tid < NXD) gstf(Vx + tid, lx[(size_t)(TSTEPS - 1) * NXD + tid]);
  }

  // per-wave prefetch regs (column gathers, fetched a step early)
  float pf0 = 0.f, pf1 = 0.f, pqa = 0.f, pr[6] = {0, 0, 0, 0, 0, 0};          // w<4
  float pA0 = 0.f, pA1 = 0.f, pB0 = 0.f, pB1 = 0.f;                            // w>=4: fx cols
  float qA0 = 0.f, qA1 = 0.f, qB0 = 0.f, qB1 = 0.f, aA = 0.f, aB = 0.f;        // lxx/lax

  auto prefetch = [&](int tn) {
    const float* fxn  = fx  + (size_t)tn * NXD * NXD;
    const float* fan  = fa  + (size_t)tn * NXD * NAD;
    const float* lxxn = lxx + (size_t)tn * NXD * NXD;
    const float* laan = laa + (size_t)tn * NAD * NAD;
    const float* laxn = lax + (size_t)tn * NAD * NXD;
    if (w < 4) {
      int j = 4 * b + w;
      pf0 = fan[lane * NAD + j]; pf1 = fan[(64 + lane) * NAD + j];
      pqa = laan[lane * NAD + j];
#pragma unroll
      for (int e = 0; e < 3; ++e) {
        int rr = 12 * b + 3 * w + e;
        if (rr < NXD) {
          pr[2 * e]     = fxn[lane * NXD + rr];
          pr[2 * e + 1] = fxn[(64 + lane) * NXD + rr];
        } else {
          int aa = rr - NXD;
          pr[2 * e]     = fan[lane * NAD + aa];
          pr[2 * e + 1] = fan[(64 + lane) * NAD + aa];
        }
      }
    } else {
      int j0 = 8 * b + 2 * (w - 4), j1 = j0 + 1;
      pA0 = fxn[lane * NXD + j0]; pA1 = fxn[(64 + lane) * NXD + j0];
      pB0 = fxn[lane * NXD + j1]; pB1 = fxn[(64 + lane) * NXD + j1];
      qA0 = lxxn[(size_t)(2 * lane) * NXD + j0];
      qA1 = lxxn[(size_t)(2 * lane + 1) * NXD + j0];
      qB0 = lxxn[(size_t)(2 * lane) * NXD + j1];
      qB1 = lxxn[(size_t)(2 * lane + 1) * NXD + j1];
      aA = laxn[lane * NXD + j0]; aB = laxn[lane * NXD + j1];
    }
  };
  prefetch(TSTEPS - 1);
  ++ep; gbar(arrive, epoch, ep);

  for (int t = TSTEPS - 1; t >= 0; --t) {
    const float* fxt = fx + (size_t)t * NXD * NXD;
    const float* fat = fa + (size_t)t * NXD * NAD;
    const float* lxt = lx + (size_t)t * NXD;
    const float* lat = la + (size_t)t * NAD;

    // ---- stage Vxx (sc1, pipelined), fa + Vx ----
    {
      const double* Vg = (const double*)Vxx;
      double* Vs = (double*)VxxS;
#pragma unroll
      for (int qq = 0; qq < 2; ++qq) {
        double r[8];
#pragma unroll
        for (int q = 0; q < 8; ++q) r[q] = gldd(Vg + tid + TPB * (8 * qq + q));
#pragma unroll
        for (int q = 0; q < 8; ++q) Vs[tid + TPB * (8 * qq + q)] = r[q];
      }
      const float4* fa4 = (const float4*)fat;
      float4* fs4 = (float4*)faS;
#pragma unroll
      for (int q = 0; q < 4; ++q) fs4[tid + TPB * q] = fa4[tid + TPB * q];
      if (tid < NXD) VxS[tid] = gldf(Vx + tid);
    }
    __syncthreads();

    // ================= PHASE 1 =================
    if (w < 4) {
      const int j = 4 * b + w;     // fa column
      float w0, w1;
      matvec128_lds(VxxS, pf0, pf1, lane, w0, w1);   // w = Vxx @ fa[:,j]
      float qa = pqa;
#pragma unroll 4
      for (int r2 = 0; r2 < 32; ++r2) {
        float t0 = rdl(w0, r2) + rdl(pf0, 2 * r2);
        float t1 = rdl(w1, r2) + rdl(pf0, 2 * r2 + 1);
        float g0 = faS[(2 * r2) * NAD + lane];
        float g1 = faS[(2 * r2 + 1) * NAD + lane];
        qa = fmaf(g0, t0, qa); qa = fmaf(g1, t1, qa);
      }
#pragma unroll 4
      for (int r2 = 32; r2 < 64; ++r2) {
        float t0 = rdl(w0, r2) + rdl(pf1, 2 * r2 - 64);
        float t1 = rdl(w1, r2) + rdl(pf1, 2 * r2 + 1 - 64);
        float g0 = faS[(2 * r2) * NAD + lane];
        float g1 = faS[(2 * r2 + 1) * NAD + lane];
        qa = fmaf(g0, t0, qa); qa = fmaf(g1, t1, qa);
      }
      gstf(QaaC + j * NAD + lane, qa);
      // Qx / Qa rows (192 rows: 12 per block, 3 per wave)
      float pv0 = VxS[lane], pv1 = VxS[64 + lane];
#pragma unroll
      for (int e = 0; e < 3; ++e) {
        int rr = 12 * b + 3 * w + e;
        float p = pr[2 * e] * pv0 + pr[2 * e + 1] * pv1;
#pragma unroll
        for (int s = 1; s < 64; s <<= 1) p += __shfl_xor(p, s);
        if (lane == 0) {
          if (rr < NXD) gstf(Qx + rr, lxt[rr] + p);
          else          gstf(Qa + rr - NXD, lat[rr - NXD] + p);
        }
      }
    } else {
      const int j0 = 8 * b + 2 * (w - 4), j1 = j0 + 1;   // fx column pair
      float wA0, wA1, wB0, wB1;
      matvec128_lds(VxxS, pA0, pA1, lane, wA0, wA1);     // Vxx @ fx[:,j0]
      matvec128_lds(VxxS, pB0, pB1, lane, wB0, wB1);     // Vxx @ fx[:,j1]
      float q0A = qA0, q1A = qA1, qaA = aA;
      float q0B = qB0, q1B = qB1, qaB = aB;
#pragma unroll 4
      for (int r2 = 0; r2 < 32; ++r2) {
        float sA0 = rdl(wA0, r2), sA1 = rdl(wA1, r2);
        float sB0 = rdl(wB0, r2), sB1 = rdl(wB1, r2);
        float tA0 = sA0 + rdl(pA0, 2 * r2),     tA1 = sA1 + rdl(pA0, 2 * r2 + 1);
        float tB0 = sB0 + rdl(pB0, 2 * r2),     tB1 = sB1 + rdl(pB0, 2 * r2 + 1);
        float2 f0 = *(const float2*)(fxt + (size_t)(2 * r2) * NXD + 2 * lane);
        float2 f1 = *(const float2*)(fxt + (size_t)(2 * r2 + 1) * NXD + 2 * lane);
        float g0 = faS[(2 * r2) * NAD + lane];
        float g1 = faS[(2 * r2 + 1) * NAD + lane];
        q0A = fmaf(f0.x, sA0, q0A); q1A = fmaf(f0.y, sA0, q1A);
        q0A = fmaf(f1.x, sA1, q0A); q1A = fmaf(f1.y, sA1, q1A);
        qaA = fmaf(g0, tA0, qaA);   qaA = fmaf(g1, tA1, qaA);
        q0B = fmaf(f0.x, sB0, q0B); q1B = fmaf(f0.y, sB0, q1B);
        q0B = fmaf(f1.x, sB1, q0B); q1B = fmaf(f1.y, sB1, q1B);
        qaB = fmaf(g0, tB0, qaB);   qaB = fmaf(g1, tB1, qaB);
      }
#pragma unroll 4
      for (int r2 = 32; r2 < 64; ++r2) {
        float sA0 = rdl(wA0, r2), sA1 = rdl(wA1, r2);
        float sB0 = rdl(wB0, r2), sB1 = rdl(wB1, r2);
        float tA0 = sA0 + rdl(pA1, 2 * r2 - 64), tA1 = sA1 + rdl(pA1, 2 * r2 + 1 - 64);
        float tB0 = sB0 + rdl(pB1, 2 * r2 - 64), tB1 = sB1 + rdl(pB1, 2 * r2 + 1 - 64);
        float2 f0 = *(const float2*)(fxt + (size_t)(2 * r2) * NXD + 2 * lane);
        float2 f1 = *(const float2*)(fxt + (size_t)(2 * r2 + 1) * NXD + 2 * lane);
        float g0 = faS[(2 * r2) * NAD + lane];
        float g1 = faS[(2 * r2 + 1) * NAD + lane];
        q0A = fmaf(f0.x, sA0, q0A); q1A = fmaf(f0.y, sA0, q1A);
        q0A = fmaf(f1.x, sA1, q0A); q1A = fmaf(f1.y, sA1, q1A);
        qaA = fmaf(g0, tA0, qaA);   qaA = fmaf(g1, tA1, qaA);
        q0B = fmaf(f0.x, sB0, q0B); q1B = fmaf(f0.y, sB0, q1B);
        q0B = fmaf(f1.x, sB1, q0B); q1B = fmaf(f1.y, sB1, q1B);
        qaB = fmaf(g0, tB0, qaB);   qaB = fmaf(g1, tB1, qaB);
      }
      gstf(QxxC + (size_t)j0 * NXD + 2 * lane, q0A);
      gstf(QxxC + (size_t)j0 * NXD + 2 * lane + 1, q1A);
      gstf(QxxC + (size_t)j1 * NXD + 2 * lane, q0B);
      gstf(QxxC + (size_t)j1 * NXD + 2 * lane + 1, q1B);
      gstf(QaxT + j0 * NAD + lane, qaA);
      gstf(QaxT + j1 * NAD + lane, qaB);
    }
    ++ep; gbar(arrive, epoch, ep);

    // ================= PHASE 2: stage, factor, trisolve =================
    if (t > 0) prefetch(t - 1);       // long-latency gathers hide under factor

    // stage QaaS (coalesced sc1)
#pragma unroll
    for (int q = 0; q < 8; ++q) {
      int idx = tid + TPB * q;        // 0..4095
      QaaS[(idx >> 6) * QSTR + (idx & 63)] = gldf(QaaC + idx);
    }
    // hoist P3 gathers
    const int il = tid >> 5, jl = tid & 31;
    const int i0 = 32 * ti + il, i1 = i0 + 16, jj = 32 * tj + jl;
    float pxij0 = gldf(QxxC + (size_t)jj * NXD + i0);
    float pxji0 = gldf(QxxC + (size_t)i0 * NXD + jj);
    float pxij1 = gldf(QxxC + (size_t)jj * NXD + i1);
    float pxji1 = gldf(QxxC + (size_t)i1 * NXD + jj);
    float pqx0 = 0.f, pqx1 = 0.f;
    if (ti == tj && jl == 0) { pqx0 = gldf(Qx + i0); pqx1 = gldf(Qx + i1); }

    // RHS slots: s<32 -> K col 32tj+s ; 32<=s<64 -> K col 32ti+(s-32) ; s==64 -> k
    float bv[9];
#pragma unroll
    for (int r = 0; r < 9; ++r) {
      int s = w + 8 * r;
      float v = 0.f;
      if (s < 65) {
        if (s == 64) v = gldf(Qa + lane);
        else {
          int c = (s < 32) ? (32 * tj + s) : (32 * ti + (s - 32));
          v = gldf(QaxT + (size_t)c * NAD + lane);
          QaxColS[s * KSTR + lane] = v;
        }
      }
      bv[r] = v;
    }
    __syncthreads();
    if (w == 0) {
      float mmax = factor32(QaaS, lane, LfS);
      if (lane == 0) flag64 = !(mmax <= 64.0f);   // catches NaN too
    }
    __syncthreads();
    if (flag64) { if (w == 0) factor64(QaaS, lane, LdS); __syncthreads(); }
    {
      float g[9];
      if (!flag64) trisolveN<float >(LfS, lane, bv, g);
      else         trisolveN<double>(LdS, lane, bv, g);
#pragma unroll
      for (int r = 0; r < 9; ++r) {
        int s = w + 8 * r;
        if (s < 65) {
          KcolS[s * KSTR + lane] = g[r];
          bool writer = (s < 32 && ti == 0) || (s == 64 && b == 0);
          if (writer) {
            int m = (s < 32) ? (1 + 32 * tj + s) : 0;
            out[(size_t)t * NAD * GAINW + (size_t)lane * GAINW + m] = g[r];
          }
        }
      }
    }
    __syncthreads();

    // ================= PHASE 3: Vxx_n = sym(Qxx) + sym(Qax^T K); Vx_n ==========
    {
      const float* qj = QaxColS + jl * KSTR;
      const float* kj = KcolS + jl * KSTR;
      const float* qi0 = QaxColS + (32 + il) * KSTR;
      const float* ki0 = KcolS + (32 + il) * KSTR;
      const float* qi1 = QaxColS + (48 + il) * KSTR;
      const float* ki1 = KcolS + (48 + il) * KSTR;
      float d1a = 0.f, d2a = 0.f, d1b = 0.f, d2b = 0.f;
#pragma unroll 4
      for (int a4 = 0; a4 < 16; ++a4) {
        float4 A = *(const float4*)(qi0 + 4 * a4);
        float4 B = *(const float4*)(kj + 4 * a4);
        float4 C = *(const float4*)(qj + 4 * a4);
        float4 D = *(const float4*)(ki0 + 4 * a4);
        float4 E = *(const float4*)(qi1 + 4 * a4);
        float4 F = *(const float4*)(ki1 + 4 * a4);
        d1a = fmaf(A.x, B.x, d1a); d1a = fmaf(A.y, B.y, d1a);
        d1a = fmaf(A.z, B.z, d1a); d1a = fmaf(A.w, B.w, d1a);
        d2a = fmaf(C.x, D.x, d2a); d2a = fmaf(C.y, D.y, d2a);
        d2a = fmaf(C.z, D.z, d2a); d2a = fmaf(C.w, D.w, d2a);
        d1b = fmaf(E.x, B.x, d1b); d1b = fmaf(E.y, B.y, d1b);
        d1b = fmaf(E.z, B.z, d1b); d1b = fmaf(E.w, B.w, d1b);
        d2b = fmaf(C.x, F.x, d2b); d2b = fmaf(C.y, F.y, d2b);
        d2b = fmaf(C.z, F.z, d2b); d2b = fmaf(C.w, F.w, d2b);
      }
      // commutative adds -> mirror block writes bitwise-identical value at (j,i)
      gstf(Vxx + (size_t)i0 * NXD + jj, 0.5f * (pxij0 + pxji0) + 0.5f * (d1a + d2a));
      gstf(Vxx + (size_t)i1 * NXD + jj, 0.5f * (pxij1 + pxji1) + 0.5f * (d1b + d2b));

      if (ti == tj && jl == 0) {
        const float* k0 = KcolS + 64 * KSTR;
        float acc0 = 0.f, acc1 = 0.f;
#pragma unroll 4
        for (int a4 = 0; a4 < 16; ++a4) {
          float4 A = *(const float4*)(qi0 + 4 * a4);
          float4 E = *(const float4*)(qi1 + 4 * a4);
          float4 B = *(const float4*)(k0 + 4 * a4);
          acc0 = fmaf(A.x, B.x, acc0); acc0 = fmaf(A.y, B.y, acc0);
          acc0 = fmaf(A.z, B.z, acc0); acc0 = fmaf(A.w, B.w, acc0);
          acc1 = fmaf(E.x, B.x, acc1); acc1 = fmaf(E.y, B.y, acc1);
          acc1 = fmaf(E.z, B.z, acc1); acc1 = fmaf(E.w, B.w, acc1);
        }
        gstf(Vx + i0, pqx0 + acc0);
        gstf(Vx + i1, pqx1 + acc1);
      }
    }
    ++ep; gbar(arrive, epoch, ep);
  }
}

extern "C" void kernel_launch(void* const* d_in, const int* in_sizes, int n_in,
                              void* d_out, int out_size, void* d_ws, size_t ws_size,
                              hipStream_t stream) {
  const float* fx  = (const float*)d_in[0];
  const float* fa  = (const float*)d_in[1];
  const float* lx  = (const float*)d_in[2];
  const float* la  = (const float*)d_in[3];
  const float* lxx = (const float*)d_in[4];
  const float* laa = (const float*)d_in[5];
  const float* lax = (const float*)d_in[6];
  float* out = (float*)d_out;

  unsigned* bar = (unsigned*)d_ws;                  // 64 words, re-zeroed each call
  float* wsf = (float*)((char*)d_ws + 32768);

  hipLaunchKernelGGL(init_bar_kernel, dim3(1), dim3(64), 0, stream, bar);
  hipLaunchKernelGGL(ilqr_main, dim3(NBLK), dim3(TPB), 0, stream,
                     fx, fa, lx, la, lxx, laa, lax, out, wsf, bar);
}